// Round 9
// baseline (110.109 us; speedup 1.0000x reference)
//
#include <hip/hip_runtime.h>
#include <math.h>

// QASA layer: out = circuit(x @ W_in.T + b_in, q_weights) @ W_out.T + b_out
// 8 qubits -> 256 complex amps. State idx = lane*4 + r: idx bits [7:2] =
// lane bits [5:0], bits [1:0] = reg. Wire i acts on idx bit 7-i.
//
// Round 9: 100% OCCUPANCY. Rounds 5-8 ran 4096 waves on an 8192-wave
// machine (<=50% occupancy) — which is why four per-wave work reductions
// were all neutral (latency-bound kernel; waves hide latency, not less
// work). This round: 4 rows/block, 1 row/wave, grid=2048 -> 8 blocks/CU,
// __launch_bounds__(256,8) forcing VGPR<=64 -> 32 waves/CU (100%).
// Phase 1 is k-outer streaming (peak live ~52 VGPR); phase-4 operands
// loaded after the circuit (no prefetch, register budget first).
//
// Circuit = round-5 verified 64-lane form verbatim: CNOT ladders eliminated
// via F=I+S conjugation (RX axis = F^a e_k, RZ sign = row_k(F^-a),
// measurement absorbs F^-4), layer 0 + embedding absorbed into per-wire
// product factors, f32x2 packed gate math.

typedef float f32x2 __attribute__((ext_vector_type(2)));

__device__ __forceinline__ int f2i(float v) { return __float_as_int(v); }
__device__ __forceinline__ float i2f(int v) { return __int_as_float(v); }

template <int CTRL>
__device__ __forceinline__ float dppf(float v) {
    return i2f(__builtin_amdgcn_update_dpp(0, f2i(v), CTRL, 0xF, 0xF, true));
}

// generalized xor-mask cross-lane: DPP where possible, ds_swizzle <32, shfl >=32
template <int ML>
__device__ __forceinline__ float gshm(float v) {
    static_assert(ML > 0 && ML < 64, "lane mask");
    if constexpr (ML == 1)      return dppf<0xB1>(v);        // quad_perm [1,0,3,2]
    else if constexpr (ML == 2) return dppf<0x4E>(v);        // quad_perm [2,3,0,1]
    else if constexpr (ML == 3) return dppf<0x1B>(v);        // quad_perm [3,2,1,0]
    else if constexpr (ML == 8) return dppf<0x128>(v);       // row_ror:8 == xor8 in 16
    else if constexpr (ML < 32) return i2f(__builtin_amdgcn_ds_swizzle(f2i(v), 0x1F | (ML << 10)));
    else                        return __shfl_xor(v, ML, 64);
}

template <int L>
__device__ __forceinline__ float rdlane(float v) {
    return i2f(__builtin_amdgcn_readlane(f2i(v), L));
}

// Generalized gate on packed state: RX(th1) about axis (lane-mask ML,
// reg-mask MR), then RZ(th2) with sign = parity(lane&ZL)^parity(r&ZR).
template <int ML, int MR, int ZL, int ZR>
__device__ __forceinline__ void ggate(f32x2& reA, f32x2& reB, f32x2& imA, f32x2& imB,
                                      float c1, float s1, float c2, float s2,
                                      int lane) {
    // ---- partner fetch: reg-swizzle by MR, then lane-xor by ML ----
    f32x2 sReA, sReB, sImA, sImB;
    if constexpr (MR == 0)      { sReA = reA;    sReB = reB;    sImA = imA;    sImB = imB; }
    else if constexpr (MR == 1) { sReA = reA.yx; sReB = reB.yx; sImA = imA.yx; sImB = imB.yx; }
    else if constexpr (MR == 2) { sReA = reB;    sReB = reA;    sImA = imB;    sImB = imA; }
    else                        { sReA = reB.yx; sReB = reA.yx; sImA = imB.yx; sImB = imA.yx; }
    f32x2 pReA, pReB, pImA, pImB;
    if constexpr (ML != 0) {
        pReA.x = gshm<ML>(sReA.x); pReA.y = gshm<ML>(sReA.y);
        pReB.x = gshm<ML>(sReB.x); pReB.y = gshm<ML>(sReB.y);
        pImA.x = gshm<ML>(sImA.x); pImA.y = gshm<ML>(sImA.y);
        pImB.x = gshm<ML>(sImB.x); pImB.y = gshm<ML>(sImB.y);
    } else { pReA = sReA; pReB = sReB; pImA = sImA; pImB = sImB; }
    // ---- RX ----
    f32x2 nReA = c1 * reA + s1 * pImA;
    f32x2 nReB = c1 * reB + s1 * pImB;
    f32x2 nImA = c1 * imA - s1 * pReA;
    f32x2 nImB = c1 * imB - s1 * pReB;
    // ---- RZ: ss_r = sigma(r) * base, base = parity(lane&ZL) ? s2 : -s2 ----
    float base;
    if constexpr (ZL == 0) base = -s2;
    else                   base = (__popc(lane & ZL) & 1) ? s2 : -s2;
    constexpr bool N1 = (ZR & 1) != 0;                       // sigma(1)
    constexpr bool N2 = ((ZR >> 1) & 1) != 0;                // sigma(2)
    constexpr bool N3 = (((ZR & 1) ^ ((ZR >> 1) & 1)) != 0); // sigma(3)
    f32x2 ssA = { base, N1 ? -base : base };
    f32x2 ssB = { N2 ? -base : base, N3 ? -base : base };
    f32x2 tA = c2 * nReA - ssA * nImA;
    f32x2 tB = c2 * nReB - ssB * nImB;
    imA = c2 * nImA + ssA * nReA;
    imB = c2 * nImB + ssB * nReB;
    reA = tA;
    reB = tB;
}

__global__ void __launch_bounds__(256, 8) qasa_kernel(
    const float* __restrict__ x, const float* __restrict__ W_in,
    const float* __restrict__ b_in, const float* __restrict__ qw,
    const float* __restrict__ W_out, const float* __restrict__ b_out,
    float* __restrict__ out)
{
    const int tid = threadIdx.x;
    const int lane = tid & 63;
    const int w = tid >> 6;                       // wave id in block (= row id)
    const int block4 = blockIdx.x * 4;

    __shared__ float ang[32];                     // [q][4 rows]
    __shared__ float evs[4][8] __attribute__((aligned(16)));  // [row][ev]

    // per-wave layer trig, lane-indexed in VGPRs (qw has exactly 64 entries)
    float vc, vs;
    __sincosf(0.5f * qw[lane], &vs, &vc);

    const int b0 = lane & 1, b1 = (lane >> 1) & 1, b3 = (lane >> 3) & 1;
    const int qofl = b0 | (b1 << 1) | (b3 << 2);  // qubit index held by this lane
    const float binq = b_in[qofl];

    // ---- phase 1 (cooperative, k-outer streaming): wave w computes angles
    //      for q = 2w, 2w+1 over the block's 4 rows. Peak live ~52 VGPR.
    {
        const float4* w4 = (const float4*)W_in;
        const float4* xr0 = (const float4*)(x + (size_t)block4 * 1024);
        f32x2 acc2[8];                             // [qp*4 + r]
#pragma unroll
        for (int j = 0; j < 8; ++j) acc2[j] = (f32x2){0.f, 0.f};
#pragma unroll
        for (int k = 0; k < 4; ++k) {
            float4 wv0 = w4[(2 * w) * 256 + lane + 64 * k];
            float4 wv1 = w4[(2 * w + 1) * 256 + lane + 64 * k];
#pragma unroll
            for (int r = 0; r < 4; ++r) {
                float4 xvv = xr0[r * 256 + lane + 64 * k];
                acc2[r]     += (f32x2){xvv.x, xvv.y} * (f32x2){wv0.x, wv0.y}
                             + (f32x2){xvv.z, xvv.w} * (f32x2){wv0.z, wv0.w};
                acc2[4 + r] += (f32x2){xvv.x, xvv.y} * (f32x2){wv1.x, wv1.y}
                             + (f32x2){xvv.z, xvv.w} * (f32x2){wv1.z, wv1.w};
            }
        }
        float acc[8];
#pragma unroll
        for (int j = 0; j < 8; ++j) {
            acc[j] = acc2[j].x + acc2[j].y;
            acc[j] += dppf<0xB1>(acc[j]);
            acc[j] += dppf<0x4E>(acc[j]);
            acc[j] += dppf<0x128>(acc[j]);
        }
        // transpose: lane picks acc[j], j = b0 | b1<<1 | b3<<2
        float t01 = b0 ? acc[1] : acc[0];
        float t23 = b0 ? acc[3] : acc[2];
        float t45 = b0 ? acc[5] : acc[4];
        float t67 = b0 ? acc[7] : acc[6];
        float ta = b1 ? t23 : t01;
        float tb = b1 ? t67 : t45;
        float S = b3 ? tb : ta;
        S += gshm<4>(S); S += gshm<16>(S); S += gshm<32>(S);
        // writer lanes {0,1,2,3,8,9,10,11}: q = 2w + b3, r = lane&3
        if ((lane & 52) == 0)
            ang[(2 * w + ((lane >> 3) & 1)) * 4 + (lane & 3)] = S;
    }
    __syncthreads();

    // ---- phase 2a: per-wire factor = RZ(qz) RX(qx) RZ(a) RX(a) |0> ----
    float A = ang[qofl * 4 + w] + binq;
    float ca, sa;
    __sincosf(0.5f * A, &sa, &ca);
    // embedding part: u = (ca^2, -ca*sa), v = (sa^2, -ca*sa)
    float ur = ca * ca, ui = -ca * sa, vr = sa * sa, vi = ui;
    const int a1 = 4 * qofl, a2 = 4 * (qofl + 8);
    float cx = i2f(__builtin_amdgcn_ds_bpermute(a1, f2i(vc)));
    float sx = i2f(__builtin_amdgcn_ds_bpermute(a1, f2i(vs)));
    float cz = i2f(__builtin_amdgcn_ds_bpermute(a2, f2i(vc)));
    float sz = i2f(__builtin_amdgcn_ds_bpermute(a2, f2i(vs)));
    // RX(qx): u' = cx*u - i sx*v ; v' = cx*v - i sx*u
    float ur1 = cx * ur + sx * vi, ui1 = cx * ui - sx * vr;
    float vr1 = cx * vr + sx * ui, vi1 = cx * vi - sx * ur;
    // RZ(qz): u'' = (cz - i sz) u' ; v'' = (cz + i sz) v'
    float ur2 = cz * ur1 + sz * ui1, ui2 = cz * ui1 - sz * ur1;
    float vr2 = cz * vr1 - sz * vi1, vi2 = cz * vi1 + sz * vr1;
    // factor for qubit q lives in lane {0,1,2,3,8,9,10,11}

    // ---- phase 2b-init: product expansion (state after layer 0) ----
    float Pr, Pi;
    {   // wire 0 (lane bit 5), factor in lane 0
        float fur = rdlane<0>(ur2), fui = rdlane<0>(ui2);
        float fvr = rdlane<0>(vr2), fvi = rdlane<0>(vi2);
        bool b = (lane >> 5) & 1;
        Pr = b ? fvr : fur;
        Pi = b ? fvi : fui;
    }
#define PMUL(W_, L_) { \
        float fur = rdlane<L_>(ur2), fui = rdlane<L_>(ui2); \
        float fvr = rdlane<L_>(vr2), fvi = rdlane<L_>(vi2); \
        bool b = (lane >> (5 - (W_))) & 1; \
        float fr = b ? fvr : fur, fi = b ? fvi : fui; \
        float tr = Pr * fr - Pi * fi; \
        Pi = Pr * fi + Pi * fr; \
        Pr = tr; }
    PMUL(1, 1) PMUL(2, 2) PMUL(3, 3) PMUL(4, 8) PMUL(5, 9)
#undef PMUL
    f32x2 reA, reB, imA, imB;
    {   // wires 6 (reg bit1, lane 10) and 7 (reg bit0, lane 11)
        float u6r = rdlane<10>(ur2), u6i = rdlane<10>(ui2);
        float v6r = rdlane<10>(vr2), v6i = rdlane<10>(vi2);
        float u7r = rdlane<11>(ur2), u7i = rdlane<11>(ui2);
        float v7r = rdlane<11>(vr2), v7i = rdlane<11>(vi2);
        float rr[4], ii[4];
#pragma unroll
        for (int r = 0; r < 4; ++r) {
            float g6r_ = (r & 2) ? v6r : u6r, g6i_ = (r & 2) ? v6i : u6i;
            float g7r_ = (r & 1) ? v7r : u7r, g7i_ = (r & 1) ? v7i : u7i;
            float fr = g6r_ * g7r_ - g6i_ * g7i_;
            float fi = g6r_ * g7i_ + g6i_ * g7r_;
            rr[r] = Pr * fr - Pi * fi;
            ii[r] = Pr * fi + Pi * fr;
        }
        reA = (f32x2){ rr[0], rr[1] };  reB = (f32x2){ rr[2], rr[3] };
        imA = (f32x2){ ii[0], ii[1] };  imB = (f32x2){ ii[2], ii[3] };
    }

    // ---- phase 2b: layers 2-4, CNOTs absorbed into gate masks ----
    // qw[l][0][i] -> lane 16l+i (RX), qw[l][1][i] -> lane 16l+8+i (RZ)
#define GG(Lx, W_, ML_, MR_, ZL_, ZR_) \
    ggate<ML_, MR_, ZL_, ZR_>(reA, reB, imA, imB, \
        rdlane<16 * (Lx) + (W_)>(vc), rdlane<16 * (Lx) + (W_)>(vs), \
        rdlane<16 * (Lx) + 8 + (W_)>(vc), rdlane<16 * (Lx) + 8 + (W_)>(vs), lane);

    // layer 2 (a=1): axis F e_k = {k,k-1}; RZ rows of F^-1 = {k..7}
    GG(1,0, 48,0, 32,0)  GG(1,1, 24,0, 48,0)  GG(1,2, 12,0, 56,0) GG(1,3, 6,0, 60,0)
    GG(1,4, 3,0, 62,0)   GG(1,5, 1,2, 63,0)   GG(1,6, 0,3, 63,2)  GG(1,7, 0,1, 63,3)
    // layer 3 (a=2): axis {k,k-2}; RZ rows of F^-2 = {k,k+2,k+4,k+6}
    GG(2,0, 40,0, 32,0)  GG(2,1, 20,0, 16,0)  GG(2,2, 10,0, 40,0) GG(2,3, 5,0, 20,0)
    GG(2,4, 2,2, 42,0)   GG(2,5, 1,1, 21,0)   GG(2,6, 0,2, 42,2)  GG(2,7, 0,1, 21,1)
    // layer 4 (a=3): axis {k,k-1,k-2,k-3}; RZ rows of F^-3 = {k,k+1,k+4,k+5}
    GG(3,0, 60,0, 32,0)  GG(3,1, 30,0, 48,0)  GG(3,2, 15,0, 24,0) GG(3,3, 7,2, 12,0)
    GG(3,4, 3,3, 38,0)   GG(3,5, 1,3, 51,0)   GG(3,6, 0,3, 25,2)  GG(3,7, 0,1, 12,3)
#undef GG

    // ---- phase 3: expvals with F^-4-absorbed masks (row_k = {k,k+4}) ----
    {
        float p0 = reA.x * reA.x + imA.x * imA.x;
        float p1 = reA.y * reA.y + imA.y * imA.y;
        float p2 = reB.x * reB.x + imB.x * imB.x;
        float p3 = reB.y * reB.y + imB.y * imB.y;
        float q0 = (p0 + p1) + (p2 + p3);
        float q2 = (p0 + p1) - (p2 + p3);   // reg-mask 2 (sign by r1)
        float q1 = (p0 + p2) - (p1 + p3);   // reg-mask 1 (sign by r0)

        // full signed Walsh butterfly on q0: lane mu ends with coeff(mask=mu)
        float v = q0;
        { float u = dppf<0xB1>(v);  v = (lane & 1)  ? (u - v) : (v + u); }
        { float u = dppf<0x4E>(v);  v = (lane & 2)  ? (u - v) : (v + u); }
        { float u = dppf<0x128>(v); v = (lane & 8)  ? (u - v) : (v + u); }
        { float u = gshm<4>(v);     v = (lane & 4)  ? (u - v) : (v + u); }
        { float u = gshm<16>(v);    v = (lane & 16) ? (u - v) : (v + u); }
        { float u = gshm<32>(v);    v = (lane & 32) ? (u - v) : (v + u); }

        // q2: coeff at lane-mask 8 (signed step at bit3 only)
        q2 += dppf<0xB1>(q2);
        q2 += dppf<0x4E>(q2);
        { float u = dppf<0x128>(q2); q2 = (lane & 8) ? (u - q2) : (q2 + u); }
        q2 += gshm<4>(q2); q2 += gshm<16>(q2); q2 += gshm<32>(q2);

        // q1: coeff at lane-mask 4 (signed step at bit2 only)
        q1 += dppf<0xB1>(q1);
        q1 += dppf<0x4E>(q1);
        q1 += dppf<0x128>(q1);
        { float u = gshm<4>(q1); q1 = (lane & 4) ? (u - q1) : (q1 + u); }
        q1 += gshm<16>(q1); q1 += gshm<32>(q1);

        // write EVs to LDS directly from their holder lanes
        const unsigned long long wrmask = 0x0000000500030110ULL; // lanes 4,8,16,17,32,34
        if ((wrmask >> lane) & 1) {
            int k = 6 - __ffs(lane);        // 32->0,16->1,8->2,4->3,34->4,17->5
            evs[w][k] = v;
        }
        if (lane == 8) { evs[w][6] = q2; }
        if (lane == 4) { evs[w][7] = q1; }
    }
    __syncthreads();

    // ---- phase 4 (cooperative): wave w owns output cols [256w, 256w+256)
    //      for the block's 4 rows; W_out slice + bias loaded once (L2-hot).
    {
        const int c4 = (w << 6) + lane;     // float4-col index; col0 = 4*c4
        const float4* wo = (const float4*)W_out;
        float4 wa[4], wb[4];
#pragma unroll
        for (int c = 0; c < 4; ++c) {
            wa[c] = wo[2 * (4 * c4 + c)];
            wb[c] = wo[2 * (4 * c4 + c) + 1];
        }
        float4 bias = ((const float4*)b_out)[c4];
#pragma unroll
        for (int r = 0; r < 4; ++r) {
            const float4* ev4 = (const float4*)evs[r];
            float4 lo = ev4[0], hi = ev4[1];
            f32x2 E01 = { lo.x, lo.y }, E23 = { lo.z, lo.w };
            f32x2 E45 = { hi.x, hi.y }, E67 = { hi.z, hi.w };
            float res[4];
#pragma unroll
            for (int c = 0; c < 4; ++c) {
                f32x2 a2v = E01 * (f32x2){ wa[c].x, wa[c].y } + E23 * (f32x2){ wa[c].z, wa[c].w }
                          + E45 * (f32x2){ wb[c].x, wb[c].y } + E67 * (f32x2){ wb[c].z, wb[c].w };
                res[c] = a2v.x + a2v.y;
            }
            float4 o;
            o.x = bias.x + res[0]; o.y = bias.y + res[1];
            o.z = bias.z + res[2]; o.w = bias.w + res[3];
            ((float4*)(out + (size_t)(block4 + r) * 1024))[c4] = o;
        }
    }
}

extern "C" void kernel_launch(void* const* d_in, const int* in_sizes, int n_in,
                              void* d_out, int out_size, void* d_ws, size_t ws_size,
                              hipStream_t stream) {
    const float* x     = (const float*)d_in[0];
    const float* W_in  = (const float*)d_in[1];
    const float* b_in  = (const float*)d_in[2];
    const float* qw    = (const float*)d_in[3];
    const float* W_out = (const float*)d_in[4];
    const float* b_out = (const float*)d_in[5];
    float* outp = (float*)d_out;

    const int B = in_sizes[0] / 1024;   // 8192 rows
    const int grid = B / 4;             // 4 rows (waves) per 256-thread block
    qasa_kernel<<<grid, 256, 0, stream>>>(x, W_in, b_in, qw, W_out, b_out, outp);
}

// Round 12
// 109.163 us; speedup vs baseline: 1.0087x; 1.0087x over previous
//
#include <hip/hip_runtime.h>
#include <math.h>

// QASA layer: out = circuit(x @ W_in.T + b_in, q_weights) @ W_out.T + b_out
// 8 qubits -> 256 complex amps. State idx = lane*4 + r: idx bits [7:2] =
// lane bits [5:0], bits [1:0] = reg. Wire i acts on idx bit 7-i.
//
// Round 12: DS-PIPE OFFLOAD, SEMANTICS-PROOF PERMLANE. Round 11's inline-asm
// permlane failed correctness (row-pairing semantics + register hazards).
// This version uses the compiler builtins and a multiset identity: with both
// operands = v, permlaneN_swap returns {v[lane], v[lane^N]} in SOME order at
// every lane (true under any complementary-row-swap semantics), so
//   xorN(v) = (pr[0] + pr[1]) - v
// needs no lane selection and is correct by construction. xor16/xor32 thus
// move from the CU-shared DS pipe to VALU; xor10 = xor8*xor2 pure DPP. Only
// xor-masks containing bit2 keep one ds_swizzle. DS ops/wave 112 -> ~72.
// Everything else = round-8 verified kernel verbatim.
//
// Circuit: CNOT ladders eliminated via F=I+S conjugation (RX axis = F^a e_k,
// RZ sign = row_k(F^-a), measurement absorbs F^-4), layer 0 + embedding
// absorbed into per-wire product factors, f32x2 packed gate math.

typedef float f32x2 __attribute__((ext_vector_type(2)));

__device__ __forceinline__ int f2i(float v) { return __float_as_int(v); }
__device__ __forceinline__ float i2f(int v) { return __int_as_float(v); }

template <int CTRL>
__device__ __forceinline__ float dppf(float v) {
    return i2f(__builtin_amdgcn_update_dpp(0, f2i(v), CTRL, 0xF, 0xF, true));
}

// xor16 via v_permlane16_swap_b32 (VALU pipe). With a=b=v the two results
// at each lane are {v[lane], v[lane^16]} in some order -> sum-minus-v is
// the xor16 partner, independent of the instruction's row-pairing order.
__device__ __forceinline__ float pl16r(float v) {
    auto pr = __builtin_amdgcn_permlane16_swap((unsigned)f2i(v), (unsigned)f2i(v), false, false);
    return (i2f((int)pr[0]) + i2f((int)pr[1])) - v;
}
// xor32 via v_permlane32_swap_b32 (VALU pipe), same identity.
__device__ __forceinline__ float pl32r(float v) {
    auto pr = __builtin_amdgcn_permlane32_swap((unsigned)f2i(v), (unsigned)f2i(v), false, false);
    return (i2f((int)pr[0]) + i2f((int)pr[1])) - v;
}

// low-5-bit xor mask: DPP for {1,2,3,8,9,10,11}; single ds_swizzle when
// bit2 set (covers all low bits); else permlane16 composed with the rest.
template <int M>
__device__ __forceinline__ float xlow(float v) {
    static_assert(M >= 0 && M < 32, "low mask");
    if constexpr (M == 0)       return v;
    else if constexpr (M == 1)  return dppf<0xB1>(v);    // quad_perm [1,0,3,2]
    else if constexpr (M == 2)  return dppf<0x4E>(v);    // quad_perm [2,3,0,1]
    else if constexpr (M == 3)  return dppf<0x1B>(v);    // quad_perm [3,2,1,0]
    else if constexpr (M == 8)  return dppf<0x128>(v);   // row_ror:8 = xor8
    else if constexpr (M == 9)  return dppf<0xB1>(dppf<0x128>(v));
    else if constexpr (M == 10) return dppf<0x4E>(dppf<0x128>(v));
    else if constexpr (M == 11) return dppf<0x1B>(dppf<0x128>(v));
    else if constexpr ((M & 4) != 0)
        return i2f(__builtin_amdgcn_ds_swizzle(f2i(v), 0x1F | (M << 10)));
    else                        return pl16r(xlow<M & 15>(v));  // bit4 + rest
}

// generalized xor-mask cross-lane; DS only when mask has bit2
template <int ML>
__device__ __forceinline__ float gshm(float v) {
    static_assert(ML > 0 && ML < 64, "lane mask");
    if constexpr (ML >= 32) return pl32r(xlow<ML & 31>(v));
    else                    return xlow<ML>(v);
}

template <int L>
__device__ __forceinline__ float rdlane(float v) {
    return i2f(__builtin_amdgcn_readlane(f2i(v), L));
}

// Generalized gate on packed state: RX(th1) about axis (lane-mask ML,
// reg-mask MR), then RZ(th2) with sign = parity(lane&ZL)^parity(r&ZR).
template <int ML, int MR, int ZL, int ZR>
__device__ __forceinline__ void ggate(f32x2& reA, f32x2& reB, f32x2& imA, f32x2& imB,
                                      float c1, float s1, float c2, float s2,
                                      int lane) {
    // ---- partner fetch: reg-swizzle by MR, then lane-xor by ML ----
    f32x2 sReA, sReB, sImA, sImB;
    if constexpr (MR == 0)      { sReA = reA;    sReB = reB;    sImA = imA;    sImB = imB; }
    else if constexpr (MR == 1) { sReA = reA.yx; sReB = reB.yx; sImA = imA.yx; sImB = imB.yx; }
    else if constexpr (MR == 2) { sReA = reB;    sReB = reA;    sImA = imB;    sImB = imA; }
    else                        { sReA = reB.yx; sReB = reA.yx; sImA = imB.yx; sImB = imA.yx; }
    f32x2 pReA, pReB, pImA, pImB;
    if constexpr (ML != 0) {
        pReA.x = gshm<ML>(sReA.x); pReA.y = gshm<ML>(sReA.y);
        pReB.x = gshm<ML>(sReB.x); pReB.y = gshm<ML>(sReB.y);
        pImA.x = gshm<ML>(sImA.x); pImA.y = gshm<ML>(sImA.y);
        pImB.x = gshm<ML>(sImB.x); pImB.y = gshm<ML>(sImB.y);
    } else { pReA = sReA; pReB = sReB; pImA = sImA; pImB = sImB; }
    // ---- RX ----
    f32x2 nReA = c1 * reA + s1 * pImA;
    f32x2 nReB = c1 * reB + s1 * pImB;
    f32x2 nImA = c1 * imA - s1 * pReA;
    f32x2 nImB = c1 * imB - s1 * pReB;
    // ---- RZ: ss_r = sigma(r) * base, base = parity(lane&ZL) ? s2 : -s2 ----
    float base;
    if constexpr (ZL == 0) base = -s2;
    else                   base = (__popc(lane & ZL) & 1) ? s2 : -s2;
    constexpr bool N1 = (ZR & 1) != 0;                       // sigma(1)
    constexpr bool N2 = ((ZR >> 1) & 1) != 0;                // sigma(2)
    constexpr bool N3 = (((ZR & 1) ^ ((ZR >> 1) & 1)) != 0); // sigma(3)
    f32x2 ssA = { base, N1 ? -base : base };
    f32x2 ssB = { N2 ? -base : base, N3 ? -base : base };
    f32x2 tA = c2 * nReA - ssA * nImA;
    f32x2 tB = c2 * nReB - ssB * nImB;
    imA = c2 * nImA + ssA * nReA;
    imB = c2 * nImB + ssB * nReB;
    reA = tA;
    reB = tB;
}

__global__ void __launch_bounds__(256, 4) qasa_kernel(
    const float* __restrict__ x, const float* __restrict__ W_in,
    const float* __restrict__ b_in, const float* __restrict__ qw,
    const float* __restrict__ W_out, const float* __restrict__ b_out,
    float* __restrict__ out)
{
    const int tid = threadIdx.x;
    const int lane = tid & 63;
    const int w = tid >> 6;                       // wave id in block (= row id)
    const int block4 = blockIdx.x * 4;

    __shared__ float ang[32];                     // [q][4 rows]
    __shared__ float evs[4][8] __attribute__((aligned(16)));  // [row][ev]

    // per-wave layer trig, lane-indexed in VGPRs (qw has exactly 64 entries)
    float vc, vs;
    __sincosf(0.5f * qw[lane], &vs, &vc);

    const int b0 = lane & 1, b1 = (lane >> 1) & 1, b3 = (lane >> 3) & 1;
    const int qofl = b0 | (b1 << 1) | (b3 << 2);  // qubit index held by this lane
    const float binq = b_in[qofl];

    // ---- phase 1 (cooperative, k-outer streaming): wave w computes angles
    //      for q = 2w, 2w+1 over the block's 4 rows.
    {
        const float4* w4 = (const float4*)W_in;
        const float4* xr0 = (const float4*)(x + (size_t)block4 * 1024);
        f32x2 acc2[8];                             // [qp*4 + r]
#pragma unroll
        for (int j = 0; j < 8; ++j) acc2[j] = (f32x2){0.f, 0.f};
#pragma unroll
        for (int k = 0; k < 4; ++k) {
            float4 wv0 = w4[(2 * w) * 256 + lane + 64 * k];
            float4 wv1 = w4[(2 * w + 1) * 256 + lane + 64 * k];
#pragma unroll
            for (int r = 0; r < 4; ++r) {
                float4 xvv = xr0[r * 256 + lane + 64 * k];
                acc2[r]     += (f32x2){xvv.x, xvv.y} * (f32x2){wv0.x, wv0.y}
                             + (f32x2){xvv.z, xvv.w} * (f32x2){wv0.z, wv0.w};
                acc2[4 + r] += (f32x2){xvv.x, xvv.y} * (f32x2){wv1.x, wv1.y}
                             + (f32x2){xvv.z, xvv.w} * (f32x2){wv1.z, wv1.w};
            }
        }
        float acc[8];
#pragma unroll
        for (int j = 0; j < 8; ++j) {
            acc[j] = acc2[j].x + acc2[j].y;
            acc[j] += dppf<0xB1>(acc[j]);
            acc[j] += dppf<0x4E>(acc[j]);
            acc[j] += dppf<0x128>(acc[j]);
        }
        // transpose: lane picks acc[j], j = b0 | b1<<1 | b3<<2
        float t01 = b0 ? acc[1] : acc[0];
        float t23 = b0 ? acc[3] : acc[2];
        float t45 = b0 ? acc[5] : acc[4];
        float t67 = b0 ? acc[7] : acc[6];
        float ta = b1 ? t23 : t01;
        float tb = b1 ? t67 : t45;
        float S = b3 ? tb : ta;
        S += gshm<4>(S); S += gshm<16>(S); S += gshm<32>(S);
        // writer lanes {0,1,2,3,8,9,10,11}: q = 2w + b3, r = lane&3
        if ((lane & 52) == 0)
            ang[(2 * w + ((lane >> 3) & 1)) * 4 + (lane & 3)] = S;
    }
    __syncthreads();

    // ---- phase 2a: per-wire factor = RZ(qz) RX(qx) RZ(a) RX(a) |0> ----
    float A = ang[qofl * 4 + w] + binq;
    float ca, sa;
    __sincosf(0.5f * A, &sa, &ca);
    // embedding part: u = (ca^2, -ca*sa), v = (sa^2, -ca*sa)
    float ur = ca * ca, ui = -ca * sa, vr = sa * sa, vi = ui;
    const int a1 = 4 * qofl, a2 = 4 * (qofl + 8);
    float cx = i2f(__builtin_amdgcn_ds_bpermute(a1, f2i(vc)));
    float sx = i2f(__builtin_amdgcn_ds_bpermute(a1, f2i(vs)));
    float cz = i2f(__builtin_amdgcn_ds_bpermute(a2, f2i(vc)));
    float sz = i2f(__builtin_amdgcn_ds_bpermute(a2, f2i(vs)));
    // RX(qx): u' = cx*u - i sx*v ; v' = cx*v - i sx*u
    float ur1 = cx * ur + sx * vi, ui1 = cx * ui - sx * vr;
    float vr1 = cx * vr + sx * ui, vi1 = cx * vi - sx * ur;
    // RZ(qz): u'' = (cz - i sz) u' ; v'' = (cz + i sz) v'
    float ur2 = cz * ur1 + sz * ui1, ui2 = cz * ui1 - sz * ur1;
    float vr2 = cz * vr1 - sz * vi1, vi2 = cz * vi1 + sz * vr1;
    // factor for qubit q lives in lane {0,1,2,3,8,9,10,11}

    // ---- phase 2b-init: product expansion (state after layer 0) ----
    float Pr, Pi;
    {   // wire 0 (lane bit 5), factor in lane 0
        float fur = rdlane<0>(ur2), fui = rdlane<0>(ui2);
        float fvr = rdlane<0>(vr2), fvi = rdlane<0>(vi2);
        bool b = (lane >> 5) & 1;
        Pr = b ? fvr : fur;
        Pi = b ? fvi : fui;
    }
#define PMUL(W_, L_) { \
        float fur = rdlane<L_>(ur2), fui = rdlane<L_>(ui2); \
        float fvr = rdlane<L_>(vr2), fvi = rdlane<L_>(vi2); \
        bool b = (lane >> (5 - (W_))) & 1; \
        float fr = b ? fvr : fur, fi = b ? fvi : fui; \
        float tr = Pr * fr - Pi * fi; \
        Pi = Pr * fi + Pi * fr; \
        Pr = tr; }
    PMUL(1, 1) PMUL(2, 2) PMUL(3, 3) PMUL(4, 8) PMUL(5, 9)
#undef PMUL
    f32x2 reA, reB, imA, imB;
    {   // wires 6 (reg bit1, lane 10) and 7 (reg bit0, lane 11)
        float u6r = rdlane<10>(ur2), u6i = rdlane<10>(ui2);
        float v6r = rdlane<10>(vr2), v6i = rdlane<10>(vi2);
        float u7r = rdlane<11>(ur2), u7i = rdlane<11>(ui2);
        float v7r = rdlane<11>(vr2), v7i = rdlane<11>(vi2);
        float rr[4], ii[4];
#pragma unroll
        for (int r = 0; r < 4; ++r) {
            float g6r_ = (r & 2) ? v6r : u6r, g6i_ = (r & 2) ? v6i : u6i;
            float g7r_ = (r & 1) ? v7r : u7r, g7i_ = (r & 1) ? v7i : u7i;
            float fr = g6r_ * g7r_ - g6i_ * g7i_;
            float fi = g6r_ * g7i_ + g6i_ * g7r_;
            rr[r] = Pr * fr - Pi * fi;
            ii[r] = Pr * fi + Pi * fr;
        }
        reA = (f32x2){ rr[0], rr[1] };  reB = (f32x2){ rr[2], rr[3] };
        imA = (f32x2){ ii[0], ii[1] };  imB = (f32x2){ ii[2], ii[3] };
    }

    // ---- phase 2b: layers 2-4, CNOTs absorbed into gate masks ----
    // qw[l][0][i] -> lane 16l+i (RX), qw[l][1][i] -> lane 16l+8+i (RZ)
#define GG(Lx, W_, ML_, MR_, ZL_, ZR_) \
    ggate<ML_, MR_, ZL_, ZR_>(reA, reB, imA, imB, \
        rdlane<16 * (Lx) + (W_)>(vc), rdlane<16 * (Lx) + (W_)>(vs), \
        rdlane<16 * (Lx) + 8 + (W_)>(vc), rdlane<16 * (Lx) + 8 + (W_)>(vs), lane);

    // layer 2 (a=1): axis F e_k = {k,k-1}; RZ rows of F^-1 = {k..7}
    GG(1,0, 48,0, 32,0)  GG(1,1, 24,0, 48,0)  GG(1,2, 12,0, 56,0) GG(1,3, 6,0, 60,0)
    GG(1,4, 3,0, 62,0)   GG(1,5, 1,2, 63,0)   GG(1,6, 0,3, 63,2)  GG(1,7, 0,1, 63,3)
    // layer 3 (a=2): axis {k,k-2}; RZ rows of F^-2 = {k,k+2,k+4,k+6}
    GG(2,0, 40,0, 32,0)  GG(2,1, 20,0, 16,0)  GG(2,2, 10,0, 40,0) GG(2,3, 5,0, 20,0)
    GG(2,4, 2,2, 42,0)   GG(2,5, 1,1, 21,0)   GG(2,6, 0,2, 42,2)  GG(2,7, 0,1, 21,1)
    // layer 4 (a=3): axis {k,k-1,k-2,k-3}; RZ rows of F^-3 = {k,k+1,k+4,k+5}
    GG(3,0, 60,0, 32,0)  GG(3,1, 30,0, 48,0)  GG(3,2, 15,0, 24,0) GG(3,3, 7,2, 12,0)
    GG(3,4, 3,3, 38,0)   GG(3,5, 1,3, 51,0)   GG(3,6, 0,3, 25,2)  GG(3,7, 0,1, 12,3)
#undef GG

    // ---- phase 3: expvals with F^-4-absorbed masks (row_k = {k,k+4}) ----
    {
        float p0 = reA.x * reA.x + imA.x * imA.x;
        float p1 = reA.y * reA.y + imA.y * imA.y;
        float p2 = reB.x * reB.x + imB.x * imB.x;
        float p3 = reB.y * reB.y + imB.y * imB.y;
        float q0 = (p0 + p1) + (p2 + p3);
        float q2 = (p0 + p1) - (p2 + p3);   // reg-mask 2 (sign by r1)
        float q1 = (p0 + p2) - (p1 + p3);   // reg-mask 1 (sign by r0)

        // full signed Walsh butterfly on q0: lane mu ends with coeff(mask=mu)
        float v = q0;
        { float u = dppf<0xB1>(v);  v = (lane & 1)  ? (u - v) : (v + u); }
        { float u = dppf<0x4E>(v);  v = (lane & 2)  ? (u - v) : (v + u); }
        { float u = dppf<0x128>(v); v = (lane & 8)  ? (u - v) : (v + u); }
        { float u = gshm<4>(v);     v = (lane & 4)  ? (u - v) : (v + u); }
        { float u = gshm<16>(v);    v = (lane & 16) ? (u - v) : (v + u); }
        { float u = gshm<32>(v);    v = (lane & 32) ? (u - v) : (v + u); }

        // q2: coeff at lane-mask 8 (signed step at bit3 only)
        q2 += dppf<0xB1>(q2);
        q2 += dppf<0x4E>(q2);
        { float u = dppf<0x128>(q2); q2 = (lane & 8) ? (u - q2) : (q2 + u); }
        q2 += gshm<4>(q2); q2 += gshm<16>(q2); q2 += gshm<32>(q2);

        // q1: coeff at lane-mask 4 (signed step at bit2 only)
        q1 += dppf<0xB1>(q1);
        q1 += dppf<0x4E>(q1);
        q1 += dppf<0x128>(q1);
        { float u = gshm<4>(q1); q1 = (lane & 4) ? (u - q1) : (q1 + u); }
        q1 += gshm<16>(q1); q1 += gshm<32>(q1);

        // write EVs to LDS directly from their holder lanes
        const unsigned long long wrmask = 0x0000000500030110ULL; // lanes 4,8,16,17,32,34
        if ((wrmask >> lane) & 1) {
            int k = 6 - __ffs(lane);        // 32->0,16->1,8->2,4->3,34->4,17->5
            evs[w][k] = v;
        }
        if (lane == 8) { evs[w][6] = q2; }
        if (lane == 4) { evs[w][7] = q1; }
    }
    __syncthreads();

    // ---- phase 4 (cooperative): wave w owns output cols [256w, 256w+256)
    //      for the block's 4 rows; W_out slice + bias loaded once (L2-hot).
    {
        const int c4 = (w << 6) + lane;     // float4-col index; col0 = 4*c4
        const float4* wo = (const float4*)W_out;
        float4 wa[4], wb[4];
#pragma unroll
        for (int c = 0; c < 4; ++c) {
            wa[c] = wo[2 * (4 * c4 + c)];
            wb[c] = wo[2 * (4 * c4 + c) + 1];
        }
        float4 bias = ((const float4*)b_out)[c4];
#pragma unroll
        for (int r = 0; r < 4; ++r) {
            const float4* ev4 = (const float4*)evs[r];
            float4 lo = ev4[0], hi = ev4[1];
            f32x2 E01 = { lo.x, lo.y }, E23 = { lo.z, lo.w };
            f32x2 E45 = { hi.x, hi.y }, E67 = { hi.z, hi.w };
            float res[4];
#pragma unroll
            for (int c = 0; c < 4; ++c) {
                f32x2 a2v = E01 * (f32x2){ wa[c].x, wa[c].y } + E23 * (f32x2){ wa[c].z, wa[c].w }
                          + E45 * (f32x2){ wb[c].x, wb[c].y } + E67 * (f32x2){ wb[c].z, wb[c].w };
                res[c] = a2v.x + a2v.y;
            }
            float4 o;
            o.x = bias.x + res[0]; o.y = bias.y + res[1];
            o.z = bias.z + res[2]; o.w = bias.w + res[3];
            ((float4*)(out + (size_t)(block4 + r) * 1024))[c4] = o;
        }
    }
}

extern "C" void kernel_launch(void* const* d_in, const int* in_sizes, int n_in,
                              void* d_out, int out_size, void* d_ws, size_t ws_size,
                              hipStream_t stream) {
    const float* x     = (const float*)d_in[0];
    const float* W_in  = (const float*)d_in[1];
    const float* b_in  = (const float*)d_in[2];
    const float* qw    = (const float*)d_in[3];
    const float* W_out = (const float*)d_in[4];
    const float* b_out = (const float*)d_in[5];
    float* outp = (float*)d_out;

    const int B = in_sizes[0] / 1024;   // 8192 rows
    const int grid = B / 4;             // 4 rows (waves) per 256-thread block
    qasa_kernel<<<grid, 256, 0, stream>>>(x, W_in, b_in, qw, W_out, b_out, outp);
}